// Round 9
// baseline (1125.415 us; speedup 1.0000x reference)
//
#include <hip/hip_runtime.h>
#include <hip/hip_bf16.h>

#define QROWS 4096
#define DDIM  768
#define NBANK 100000
#define CDIM  1000
#define KTOP  100
#define NPAD  102400                 // padded bank cols
#define SEGW2 12800                  // NPAD/8 keys per top-k segment
#define LCAP2 4096                   // LDS candidate cap in topk_seg

typedef float floatx4 __attribute__((ext_vector_type(4)));
typedef short bf16x8 __attribute__((ext_vector_type(8)));

__device__ inline ushort f2bf(float f) {            // f32 -> bf16 RNE
  uint b = __float_as_uint(f);
  uint r = b + 0x7fffu + ((b >> 16) & 1u);
  return (ushort)(r >> 16);
}
__device__ inline float o16f(ushort u) {            // ordered u16 -> f32 value
  ushort b = (u & 0x8000) ? (ushort)(u & 0x7fff) : (ushort)~u;
  return __uint_as_float((uint)b << 16);
}

// ---- row-wise logsumexp (ncols<=1024), 1 wave/row: used for bank conf AND energy
__global__ __launch_bounds__(256) void lse_rows(const float* __restrict__ x,
                                                float* __restrict__ out,
                                                int nrows, int ncols) {
  int row = blockIdx.x * 4 + (threadIdx.x >> 6);
  int lane = threadIdx.x & 63;
  if (row >= nrows) return;
  const float4* rp = (const float4*)(x + (size_t)row * ncols);
  int n4 = ncols >> 2;
  float4 v[4];
  float m = -3.0e38f;
#pragma unroll
  for (int j = 0; j < 4; j++) {
    int idx = lane + j * 64;
    if (idx < n4) {
      v[j] = rp[idx];
      m = fmaxf(m, fmaxf(fmaxf(v[j].x, v[j].y), fmaxf(v[j].z, v[j].w)));
    } else {
      v[j] = make_float4(-3.0e38f, -3.0e38f, -3.0e38f, -3.0e38f);
    }
  }
#pragma unroll
  for (int off = 32; off; off >>= 1) m = fmaxf(m, __shfl_xor(m, off));
  float s = 0.f;
#pragma unroll
  for (int j = 0; j < 4; j++)
    s += __expf(v[j].x - m) + __expf(v[j].y - m) +
         __expf(v[j].z - m) + __expf(v[j].w - m);
#pragma unroll
  for (int off = 32; off; off >>= 1) s += __shfl_xor(s, off);
  if (lane == 0) out[row] = m + __logf(s);
}

// ---- bank_sc: b16[row] = bf16(feas * conf/||feas||), zero pad rows -------
__global__ __launch_bounds__(256) void bank_sc(const float* __restrict__ feas,
                                               const float* __restrict__ conf,
                                               ushort* __restrict__ b16) {
  int row = blockIdx.x * 4 + (threadIdx.x >> 6);
  int lane = threadIdx.x & 63;
  if (row >= NPAD) return;
  ushort4* dst = (ushort4*)(b16 + (size_t)row * DDIM);
  if (row >= NBANK) {
#pragma unroll
    for (int j = 0; j < 3; j++) dst[lane + j * 64] = make_ushort4(0, 0, 0, 0);
    return;
  }
  const float4* fp = (const float4*)(feas + (size_t)row * DDIM);
  float4 w[3];
  float ss = 0.f;
#pragma unroll
  for (int j = 0; j < 3; j++) {
    w[j] = fp[lane + j * 64];
    ss += w[j].x * w[j].x + w[j].y * w[j].y + w[j].z * w[j].z + w[j].w * w[j].w;
  }
#pragma unroll
  for (int off = 32; off; off >>= 1) ss += __shfl_xor(ss, off);
  float s = conf[row] / sqrtf(ss);
#pragma unroll
  for (int j = 0; j < 3; j++)
    dst[lane + j * 64] = make_ushort4(f2bf(w[j].x * s), f2bf(w[j].y * s),
                                      f2bf(w[j].z * s), f2bf(w[j].w * s));
}

// ---- a16[q][d] = bf16(feature/||feature||) -------------------------------
__global__ __launch_bounds__(256) void feat_norm(const float* __restrict__ x,
                                                 ushort* __restrict__ y) {
  int row = blockIdx.x * 4 + (threadIdx.x >> 6);
  int lane = threadIdx.x & 63;
  if (row >= QROWS) return;
  const float4* rp = (const float4*)(x + (size_t)row * DDIM);
  float4 v[3];
  float ss = 0.f;
#pragma unroll
  for (int j = 0; j < 3; j++) {
    v[j] = rp[lane + j * 64];
    ss += v[j].x * v[j].x + v[j].y * v[j].y + v[j].z * v[j].z + v[j].w * v[j].w;
  }
#pragma unroll
  for (int off = 32; off; off >>= 1) ss += __shfl_xor(ss, off);
  float rn = 1.0f / sqrtf(ss);
  ushort4* dst = (ushort4*)(y + (size_t)row * DDIM);
#pragma unroll
  for (int j = 0; j < 3; j++)
    dst[lane + j * 64] = make_ushort4(f2bf(v[j].x * rn), f2bf(v[j].y * rn),
                                      f2bf(v[j].z * rn), f2bf(v[j].w * rn));
}

// ---- bf16 MFMA GEMM v6: m201 8-phase schedule, 256x256, BK=64 -------------
// 8 waves (2M x 4N), per-wave 128x64, 2 K-tiles/iteration, 8 phases/iter.
// Per phase: {ds_read quadrant frags; stage 1 half-tile; barrier; lgkmcnt(0);
// sched_barrier; setprio(1); 16 MFMA; setprio(0); [vmcnt(4) at ph4/ph8];
// barrier}. 3-bit XOR swizzle (0-conflict, verified r6). Counted vmcnt only.
#define GBM 256
#define GBN 256
#define GBK 64
#define NT  (DDIM / GBK)                       // 12 K-tiles, 6 iterations
#define GNWG ((QROWS / GBM) * (NPAD / GBN))    // 16*400 = 6400

__device__ inline void load_lds16(const void* g, void* l) {
  __builtin_amdgcn_global_load_lds(
      (const __attribute__((address_space(1))) void*)g,
      (__attribute__((address_space(3))) void*)l, 16, 0, 0);
}

// PHASE: BUF/Q are literals (acc indices must be compile-time, rule #20).
#define PHASE(BUF, Q, LOADB, STAGE_STMT, VM_STMT)                              \
  {                                                                            \
    const ushort* Ab = lds + (BUF) * 32768;                                    \
    if (LOADB) {                                                               \
      const ushort* Bb = Ab + 16384;                                           \
      _Pragma("unroll") for (int n = 0; n < 4; n++)                            \
        _Pragma("unroll") for (int kk = 0; kk < 2; kk++)                       \
          bfr[n][kk] = *(const bf16x8*)(Bb + (wn * 64 + n * 16 + lr) * 64 +    \
                                        ((kk * 32 + lg * 8) ^ rsw));           \
    }                                                                          \
    bf16x8 af[2][2];                                                           \
    _Pragma("unroll") for (int m = 0; m < 2; m++)                              \
      _Pragma("unroll") for (int kk = 0; kk < 2; kk++)                         \
        af[m][kk] = *(const bf16x8*)(Ab + (wm * 128 + (2 * (Q) + m) * 16 + lr) \
                                     * 64 + ((kk * 32 + lg * 8) ^ rsw));       \
    STAGE_STMT;                                                                \
    __builtin_amdgcn_s_barrier();                                              \
    asm volatile("s_waitcnt lgkmcnt(0)" ::: "memory");                         \
    __builtin_amdgcn_sched_barrier(0);                                         \
    __builtin_amdgcn_s_setprio(1);                                             \
    _Pragma("unroll") for (int m = 0; m < 2; m++)                              \
      _Pragma("unroll") for (int n = 0; n < 4; n++)                            \
        _Pragma("unroll") for (int kk = 0; kk < 2; kk++)                       \
          acc[2 * (Q) + m][n] = __builtin_amdgcn_mfma_f32_16x16x32_bf16(       \
              af[m][kk], bfr[n][kk], acc[2 * (Q) + m][n], 0, 0, 0);            \
    __builtin_amdgcn_s_setprio(0);                                             \
    VM_STMT;                                                                   \
    __builtin_amdgcn_s_barrier();                                              \
  }

__global__ __launch_bounds__(512) void gemm_sims(const ushort* __restrict__ A,
                                                 const ushort* __restrict__ B,
                                                 ushort* __restrict__ C) {
  __shared__ ushort lds[2 * 32768];            // 2 bufs x (A 16K | B 16K) ushorts
  const int tid = threadIdx.x;
  const int lane = tid & 63;
  const int wid = tid >> 6;
  const int wm = wid >> 2, wn = wid & 3;       // 2(M) x 4(N) waves, 128x64 each
  const int lr = lane & 15, lg = lane >> 4;

  // XCD chunking (6400%8==0, bijective) + 4x4 supertiles
  int flat = blockIdx.x;
  int wgid = (flat & 7) * (GNWG / 8) + (flat >> 3);
  int sup = wgid >> 4, wi = wgid & 15;
  int q_idx = (sup & 3) * 4 + (wi & 3);        // 0..15
  int n_idx = (sup >> 2) * 4 + (wi >> 2);      // 0..399
  const int qBase = q_idx * GBM;
  const int nBase = n_idx * GBN;

  // staging: 8-row groups; LDS dest linear; source col pre-swizzled (rule #21)
  const int rin = lane >> 3;
  const int cswu = ((lane & 7) ^ rin) << 3;    // ushort offset in 64-ushort row
  const int rsw = (lr & 7) << 3;               // read-side ushort xor

  // half h of A-tile t -> groups G in [16h,16h+16); buf = t&1
  auto stageAh = [&](int t, int h) {
    if (t < NT) {
#pragma unroll
      for (int r = 2 * h; r < 2 * h + 2; r++) {
        int G = r * 8 + wid;
        int row = qBase + G * 8 + rin;
        load_lds16(A + (size_t)row * DDIM + t * GBK + cswu,
                   lds + (t & 1) * 32768 + G * 512 + lane * 8);
      }
    }
  };
  auto stageBh = [&](int t, int h) {
    if (t < NT) {
#pragma unroll
      for (int r = 2 * h; r < 2 * h + 2; r++) {
        int G = r * 8 + wid;
        int row = nBase + G * 8 + rin;
        load_lds16(B + (size_t)row * DDIM + t * GBK + cswu,
                   lds + (t & 1) * 32768 + 16384 + G * 512 + lane * 8);
      }
    }
  };

  floatx4 acc[8][4] = {};
  bf16x8 bfr[4][2];

  // prologue: B(0), A(0), B(1) staged in steady-state issue order
  stageBh(0, 0); stageBh(0, 1);
  stageAh(0, 0); stageAh(0, 1);
  stageBh(1, 0); stageBh(1, 1);
  asm volatile("s_waitcnt vmcnt(4)" ::: "memory");   // A(0),B(0) landed
  __builtin_amdgcn_s_barrier();

#pragma unroll 1
  for (int i = 0; i < NT / 2; i++) {
    const int t0 = 2 * i;
    const bool last = (i == NT / 2 - 1);
    // tile t0 (buf 0)
    PHASE(0, 0, true,  stageAh(t0 + 1, 0), );
    PHASE(0, 1, false, stageAh(t0 + 1, 1), );
    PHASE(0, 2, false, stageBh(t0 + 2, 0), );
    PHASE(0, 3, false, stageBh(t0 + 2, 1),
          if (last) { asm volatile("s_waitcnt vmcnt(0)" ::: "memory"); }
          else      { asm volatile("s_waitcnt vmcnt(4)" ::: "memory"); });
    // tile t0+1 (buf 1)
    PHASE(1, 0, true,  stageAh(t0 + 2, 0), );
    PHASE(1, 1, false, stageAh(t0 + 2, 1), );
    PHASE(1, 2, false, stageBh(t0 + 3, 0), );
    PHASE(1, 3, false, stageBh(t0 + 3, 1),
          if (!last) { asm volatile("s_waitcnt vmcnt(4)" ::: "memory"); });
  }

  // epilogue: C write (bf16)
#pragma unroll
  for (int m = 0; m < 8; m++)
#pragma unroll
    for (int n = 0; n < 4; n++) {
      int q = qBase + wm * 128 + m * 16 + lg * 4;
      int col = nBase + wn * 64 + n * 16 + lr;
      ushort* cp = C + (size_t)q * NPAD + col;
#pragma unroll
      for (int r = 0; r < 4; r++) cp[(size_t)r * NPAD] = f2bf(acc[m][n][r]);
    }
}

// ---- per-segment exact top-K multiset: ballot counting + ballot compaction
__global__ __launch_bounds__(256) void topk_seg(const ushort* __restrict__ sims,
                                                ushort* __restrict__ cand) {
  __shared__ ushort smax[256];
  __shared__ ushort list[LCAP2];
  __shared__ int shC, shM, ipart[4];
  const int t = threadIdx.x;
  const int lane = t & 63;
  const int q = blockIdx.x >> 3, seg = blockIdx.x & 7;
  const ushort* base = sims + (size_t)q * NPAD + seg * SEGW2;

  uint v[25];                                  // 50 ordered u16 keys
#pragma unroll
  for (int i = 0; i < 6; i++) {                // 6 x uint4 = 48 keys
    uint4 w = ((const uint4*)base)[i * 256 + t];
    uint ww[4] = {w.x, w.y, w.z, w.w};
#pragma unroll
    for (int e = 0; e < 4; e++) {
      uint u = ww[e];
      uint mm = ((u >> 15) & 0x00010001u) * 0xffffu;
      v[4 * i + e] = (u ^ mm) | (0x80008000u & ~mm);
    }
    if (seg == 7 && (i * 256 + t) >= 1300) {   // pad cols >= 100000
      v[4 * i] = 0; v[4 * i + 1] = 0; v[4 * i + 2] = 0; v[4 * i + 3] = 0;
    }
  }
  {                                            // tail: 2 keys (invalid in seg 7)
    if (seg == 7) {
      v[24] = 0;
    } else {
      uint u = ((const uint*)base)[6144 + t];
      uint mm = ((u >> 15) & 0x00010001u) * 0xffffu;
      v[24] = (u ^ mm) | (0x80008000u & ~mm);
    }
  }
  // thread max
  uint mx = 0;
#pragma unroll
  for (int i = 0; i < 25; i++) {
    uint a = v[i] & 0xffffu, b = v[i] >> 16;
    mx = a > mx ? a : mx;
    mx = b > mx ? b : mx;
  }
  smax[t] = (ushort)mx;
  if (t == 0) shC = 0;
  __syncthreads();

  // L = 100th largest of 256 thread maxima — ballot-popcount counting
  uint m0 = smax[lane], m1 = smax[lane + 64], m2 = smax[lane + 128], m3 = smax[lane + 192];
  uint lo = 0, hi = 65536;
  while (hi - lo > 1) {
    uint mid = (lo + hi) >> 1;
    int c = __popcll(__ballot(m0 >= mid)) + __popcll(__ballot(m1 >= mid)) +
            __popcll(__ballot(m2 >= mid)) + __popcll(__ballot(m3 >= mid));
    if (c >= KTOP) lo = mid; else hi = mid;
  }
  const uint L = lo;

  // ---- ballot compaction of keys >= L into LDS (1 atomic per wave) ----
  const unsigned long long ltm = (1ull << lane) - 1ull;
  int tot = 0;
#pragma unroll
  for (int i = 0; i < 25; i++) {
    tot += __popcll(__ballot((v[i] & 0xffffu) >= L));
    tot += __popcll(__ballot((v[i] >> 16) >= L));
  }
  int wb = 0;
  if (lane == 0) wb = atomicAdd(&shC, tot);
  wb = __shfl(wb, 0);
  int run = wb;
#pragma unroll
  for (int i = 0; i < 25; i++) {
    uint a = v[i] & 0xffffu, b = v[i] >> 16;
    unsigned long long ma = __ballot(a >= L);
    if (a >= L) { int p = run + __popcll(ma & ltm); if (p < LCAP2) list[p] = (ushort)a; }
    run += __popcll(ma);
    unsigned long long mb = __ballot(b >= L);
    if (b >= L) { int p = run + __popcll(mb & ltm); if (p < LCAP2) list[p] = (ushort)b; }
    run += __popcll(mb);
  }
  __syncthreads();
  const int C = shC;

  uint Tkey;
  if (C <= LCAP2) {                            // common path: ballot-count search
    uint lo2 = L, hi2 = 65536;
    while (hi2 - lo2 > 1) {
      uint mid = (lo2 + hi2) >> 1;
      int c = 0;
      for (int j = 0; j < C; j += 64) {
        bool p = (j + lane < C) && ((uint)list[j + lane] >= mid);
        c += __popcll(__ballot(p));
      }
      if (c >= KTOP) lo2 = mid; else hi2 = mid;
    }
    Tkey = lo2;
  } else {                                     // rare fallback: regs + barriers
    uint lo2 = L, hi2 = 65536;
    while (hi2 - lo2 > 1) {
      uint mid = (lo2 + hi2) >> 1;
      int c = 0;
#pragma unroll
      for (int i = 0; i < 25; i++) {
        c += ((v[i] & 0xffffu) >= mid) ? 1 : 0;
        c += ((v[i] >> 16) >= mid) ? 1 : 0;
      }
#pragma unroll
      for (int off = 32; off; off >>= 1) c += __shfl_xor(c, off);
      __syncthreads();
      if (lane == 0) ipart[t >> 6] = c;
      __syncthreads();
      c = ipart[0] + ipart[1] + ipart[2] + ipart[3];
      if (c >= KTOP) lo2 = mid; else hi2 = mid;
    }
    Tkey = lo2;
  }

  // emit segment top-100 multiset (m <= 99 strict keys + tie fill)
  if (t == 0) shM = 0;
  __syncthreads();
  ushort* dst = cand + (size_t)q * 1024 + seg * 128;
  if (C <= LCAP2) {
    for (int i = t; i < C; i += 256) {
      uint u = list[i];
      if (u > Tkey) { int p = atomicAdd(&shM, 1); dst[p] = (ushort)u; }
    }
  } else {
#pragma unroll
    for (int i = 0; i < 25; i++) {
      uint a = v[i] & 0xffffu, b = v[i] >> 16;
      if (a > Tkey) { int p = atomicAdd(&shM, 1); dst[p] = (ushort)a; }
      if (b > Tkey) { int p = atomicAdd(&shM, 1); dst[p] = (ushort)b; }
    }
  }
  __syncthreads();
  for (int i = shM + t; i < KTOP; i += 256) dst[i] = (ushort)Tkey;
}

// ---- merge 8x100 candidates + mean + energy -> out (1 wave / row) --------
__global__ __launch_bounds__(64) void topk_fin(const ushort* __restrict__ cand,
                                               const float* __restrict__ energy,
                                               float* __restrict__ out) {
  const int q = blockIdx.x;
  const int t = threadIdx.x;
  const ushort* row = cand + (size_t)q * 1024;
  ushort kk[16];
#pragma unroll
  for (int s = 0; s < 8; s++) {
    kk[2 * s]     = row[s * 128 + t];                                  // t < 100
    kk[2 * s + 1] = (t + 64 < KTOP) ? row[s * 128 + 64 + t] : (ushort)0;
  }
  uint lo = 0, hi = 65536;
  while (hi - lo > 1) {
    uint mid = (lo + hi) >> 1;
    int c = 0;
#pragma unroll
    for (int i = 0; i < 16; i++) c += ((uint)kk[i] >= mid) ? 1 : 0;
#pragma unroll
    for (int off = 32; off; off >>= 1) c += __shfl_xor(c, off);
    if (c >= KTOP) lo = mid; else hi = mid;
  }
  const uint T = lo;
  float s = 0.f;
  int m = 0;
#pragma unroll
  for (int i = 0; i < 16; i++) {
    if ((uint)kk[i] > T) { s += o16f(kk[i]); m++; }
  }
#pragma unroll
  for (int off = 32; off; off >>= 1) {
    s += __shfl_xor(s, off);
    m += __shfl_xor(m, off);
  }
  if (t == 0) {
    float total = s + (float)(KTOP - m) * o16f((ushort)T);
    out[q] = -(total * (1.0f / KTOP)) * energy[q];
  }
}

extern "C" void kernel_launch(void* const* d_in, const int* in_sizes, int n_in,
                              void* d_out, int out_size, void* d_ws, size_t ws_size,
                              hipStream_t stream) {
  const float* feature     = (const float*)d_in[0];
  const float* logit       = (const float*)d_in[1];
  const float* bank_feas   = (const float*)d_in[2];
  const float* bank_logits = (const float*)d_in[3];
  // d_in[4] is K (device scalar) — problem instance fixes K = 100 (KTOP).
  float* out = (float*)d_out;

  char* ws = (char*)d_ws;
  size_t off = 0;
  auto take = [&](size_t bytes) -> char* {
    char* p = ws + off;
    off = (off + bytes + 255) & ~(size_t)255;
    return p;
  };
  float*  energy = (float*)take((size_t)QROWS * 4);
  float*  conf   = (float*)take((size_t)NPAD * 4);
  ushort* a16    = (ushort*)take((size_t)QROWS * DDIM * 2);
  ushort* b16    = (ushort*)take((size_t)NPAD * DDIM * 2);
  ushort* sims   = (ushort*)take((size_t)QROWS * NPAD * 2);
  ushort* cand   = (ushort*)take((size_t)QROWS * 1024 * 2);
  if (off > ws_size) return;  // needs ~1.02 GB

  lse_rows <<<dim3((NBANK + 3) / 4), dim3(256), 0, stream>>>(bank_logits, conf, NBANK, CDIM);
  bank_sc  <<<dim3(NPAD / 4), dim3(256), 0, stream>>>(bank_feas, conf, b16);
  lse_rows <<<dim3(QROWS / 4), dim3(256), 0, stream>>>(logit, energy, QROWS, CDIM);
  feat_norm<<<dim3(QROWS / 4), dim3(256), 0, stream>>>(feature, a16);
  gemm_sims<<<dim3(GNWG), dim3(512), 0, stream>>>(a16, b16, sims);
  topk_seg <<<dim3(QROWS * 8), dim3(256), 0, stream>>>(sims, cand);
  topk_fin <<<dim3(QROWS), dim3(64), 0, stream>>>(cand, energy, out);
}

// Round 10
// 1120.607 us; speedup vs baseline: 1.0043x; 1.0043x over previous
//
#include <hip/hip_runtime.h>
#include <hip/hip_bf16.h>

#define QROWS 4096
#define DDIM  768
#define NBANK 100000
#define CDIM  1000
#define KTOP  100
#define NPAD  102400                 // padded bank cols
#define SEGW2 12800                  // NPAD/8 keys per top-k segment
#define LCAP2 4096                   // LDS candidate cap in topk_seg

typedef float floatx4 __attribute__((ext_vector_type(4)));
typedef short bf16x8 __attribute__((ext_vector_type(8)));

__device__ inline ushort f2bf(float f) {            // f32 -> bf16 RNE
  uint b = __float_as_uint(f);
  uint r = b + 0x7fffu + ((b >> 16) & 1u);
  return (ushort)(r >> 16);
}
__device__ inline float o16f(ushort u) {            // ordered u16 -> f32 value
  ushort b = (u & 0x8000) ? (ushort)(u & 0x7fff) : (ushort)~u;
  return __uint_as_float((uint)b << 16);
}

// ---- row-wise logsumexp (ncols<=1024), 1 wave/row: used for bank conf AND energy
__global__ __launch_bounds__(256) void lse_rows(const float* __restrict__ x,
                                                float* __restrict__ out,
                                                int nrows, int ncols) {
  int row = blockIdx.x * 4 + (threadIdx.x >> 6);
  int lane = threadIdx.x & 63;
  if (row >= nrows) return;
  const float4* rp = (const float4*)(x + (size_t)row * ncols);
  int n4 = ncols >> 2;
  float4 v[4];
  float m = -3.0e38f;
#pragma unroll
  for (int j = 0; j < 4; j++) {
    int idx = lane + j * 64;
    if (idx < n4) {
      v[j] = rp[idx];
      m = fmaxf(m, fmaxf(fmaxf(v[j].x, v[j].y), fmaxf(v[j].z, v[j].w)));
    } else {
      v[j] = make_float4(-3.0e38f, -3.0e38f, -3.0e38f, -3.0e38f);
    }
  }
#pragma unroll
  for (int off = 32; off; off >>= 1) m = fmaxf(m, __shfl_xor(m, off));
  float s = 0.f;
#pragma unroll
  for (int j = 0; j < 4; j++)
    s += __expf(v[j].x - m) + __expf(v[j].y - m) +
         __expf(v[j].z - m) + __expf(v[j].w - m);
#pragma unroll
  for (int off = 32; off; off >>= 1) s += __shfl_xor(s, off);
  if (lane == 0) out[row] = m + __logf(s);
}

// ---- bank_sc: b16[row] = bf16(feas * conf/||feas||), zero pad rows -------
__global__ __launch_bounds__(256) void bank_sc(const float* __restrict__ feas,
                                               const float* __restrict__ conf,
                                               ushort* __restrict__ b16) {
  int row = blockIdx.x * 4 + (threadIdx.x >> 6);
  int lane = threadIdx.x & 63;
  if (row >= NPAD) return;
  ushort4* dst = (ushort4*)(b16 + (size_t)row * DDIM);
  if (row >= NBANK) {
#pragma unroll
    for (int j = 0; j < 3; j++) dst[lane + j * 64] = make_ushort4(0, 0, 0, 0);
    return;
  }
  const float4* fp = (const float4*)(feas + (size_t)row * DDIM);
  float4 w[3];
  float ss = 0.f;
#pragma unroll
  for (int j = 0; j < 3; j++) {
    w[j] = fp[lane + j * 64];
    ss += w[j].x * w[j].x + w[j].y * w[j].y + w[j].z * w[j].z + w[j].w * w[j].w;
  }
#pragma unroll
  for (int off = 32; off; off >>= 1) ss += __shfl_xor(ss, off);
  float s = conf[row] / sqrtf(ss);
#pragma unroll
  for (int j = 0; j < 3; j++)
    dst[lane + j * 64] = make_ushort4(f2bf(w[j].x * s), f2bf(w[j].y * s),
                                      f2bf(w[j].z * s), f2bf(w[j].w * s));
}

// ---- a16[q][d] = bf16(feature/||feature||) -------------------------------
__global__ __launch_bounds__(256) void feat_norm(const float* __restrict__ x,
                                                 ushort* __restrict__ y) {
  int row = blockIdx.x * 4 + (threadIdx.x >> 6);
  int lane = threadIdx.x & 63;
  if (row >= QROWS) return;
  const float4* rp = (const float4*)(x + (size_t)row * DDIM);
  float4 v[3];
  float ss = 0.f;
#pragma unroll
  for (int j = 0; j < 3; j++) {
    v[j] = rp[lane + j * 64];
    ss += v[j].x * v[j].x + v[j].y * v[j].y + v[j].z * v[j].z + v[j].w * v[j].w;
  }
#pragma unroll
  for (int off = 32; off; off >>= 1) ss += __shfl_xor(ss, off);
  float rn = 1.0f / sqrtf(ss);
  ushort4* dst = (ushort4*)(y + (size_t)row * DDIM);
#pragma unroll
  for (int j = 0; j < 3; j++)
    dst[lane + j * 64] = make_ushort4(f2bf(v[j].x * rn), f2bf(v[j].y * rn),
                                      f2bf(v[j].z * rn), f2bf(v[j].w * rn));
}

// ---- bf16 MFMA GEMM v6: m201 8-phase schedule, 256x256, BK=64 -------------
// 8 waves (2M x 4N), per-wave 128x64, 2 K-tiles/iteration, 8 phases/iter.
// Per phase: {ds_read quadrant frags; stage 1 half-tile; barrier; lgkmcnt(0);
// sched_barrier; setprio(1); 16 MFMA; setprio(0); [vmcnt(4) at ph4/ph8];
// barrier}. 3-bit XOR swizzle (0-conflict, verified r6). Counted vmcnt only.
#define GBM 256
#define GBN 256
#define GBK 64
#define NT  (DDIM / GBK)                       // 12 K-tiles, 6 iterations
#define GNWG ((QROWS / GBM) * (NPAD / GBN))    // 16*400 = 6400

__device__ inline void load_lds16(const void* g, void* l) {
  __builtin_amdgcn_global_load_lds(
      (const __attribute__((address_space(1))) void*)g,
      (__attribute__((address_space(3))) void*)l, 16, 0, 0);
}

// PHASE: BUF/Q are literals (acc indices must be compile-time, rule #20).
#define PHASE(BUF, Q, LOADB, STAGE_STMT, VM_STMT)                              \
  {                                                                            \
    const ushort* Ab = lds + (BUF) * 32768;                                    \
    if (LOADB) {                                                               \
      const ushort* Bb = Ab + 16384;                                           \
      _Pragma("unroll") for (int n = 0; n < 4; n++)                            \
        _Pragma("unroll") for (int kk = 0; kk < 2; kk++)                       \
          bfr[n][kk] = *(const bf16x8*)(Bb + (wn * 64 + n * 16 + lr) * 64 +    \
                                        ((kk * 32 + lg * 8) ^ rsw));           \
    }                                                                          \
    bf16x8 af[2][2];                                                           \
    _Pragma("unroll") for (int m = 0; m < 2; m++)                              \
      _Pragma("unroll") for (int kk = 0; kk < 2; kk++)                         \
        af[m][kk] = *(const bf16x8*)(Ab + (wm * 128 + (2 * (Q) + m) * 16 + lr) \
                                     * 64 + ((kk * 32 + lg * 8) ^ rsw));       \
    STAGE_STMT;                                                                \
    __builtin_amdgcn_s_barrier();                                              \
    asm volatile("s_waitcnt lgkmcnt(0)" ::: "memory");                         \
    __builtin_amdgcn_sched_barrier(0);                                         \
    __builtin_amdgcn_s_setprio(1);                                             \
    _Pragma("unroll") for (int m = 0; m < 2; m++)                              \
      _Pragma("unroll") for (int n = 0; n < 4; n++)                            \
        _Pragma("unroll") for (int kk = 0; kk < 2; kk++)                       \
          acc[2 * (Q) + m][n] = __builtin_amdgcn_mfma_f32_16x16x32_bf16(       \
              af[m][kk], bfr[n][kk], acc[2 * (Q) + m][n], 0, 0, 0);            \
    __builtin_amdgcn_s_setprio(0);                                             \
    VM_STMT;                                                                   \
    __builtin_amdgcn_s_barrier();                                              \
  }

__global__ __launch_bounds__(512) void gemm_sims(const ushort* __restrict__ A,
                                                 const ushort* __restrict__ B,
                                                 ushort* __restrict__ C) {
  __shared__ ushort lds[2 * 32768];            // 2 bufs x (A 16K | B 16K) ushorts
  const int tid = threadIdx.x;
  const int lane = tid & 63;
  const int wid = tid >> 6;
  const int wm = wid >> 2, wn = wid & 3;       // 2(M) x 4(N) waves, 128x64 each
  const int lr = lane & 15, lg = lane >> 4;

  // XCD chunking (6400%8==0, bijective) + 4x4 supertiles
  int flat = blockIdx.x;
  int wgid = (flat & 7) * (GNWG / 8) + (flat >> 3);
  int sup = wgid >> 4, wi = wgid & 15;
  int q_idx = (sup & 3) * 4 + (wi & 3);        // 0..15
  int n_idx = (sup >> 2) * 4 + (wi >> 2);      // 0..399
  const int qBase = q_idx * GBM;
  const int nBase = n_idx * GBN;

  // staging: 8-row groups; LDS dest linear; source col pre-swizzled (rule #21)
  const int rin = lane >> 3;
  const int cswu = ((lane & 7) ^ rin) << 3;    // ushort offset in 64-ushort row
  const int rsw = (lr & 7) << 3;               // read-side ushort xor

  // half h of A-tile t -> groups G in [16h,16h+16); buf = t&1
  auto stageAh = [&](int t, int h) {
    if (t < NT) {
#pragma unroll
      for (int r = 2 * h; r < 2 * h + 2; r++) {
        int G = r * 8 + wid;
        int row = qBase + G * 8 + rin;
        load_lds16(A + (size_t)row * DDIM + t * GBK + cswu,
                   lds + (t & 1) * 32768 + G * 512 + lane * 8);
      }
    }
  };
  auto stageBh = [&](int t, int h) {
    if (t < NT) {
#pragma unroll
      for (int r = 2 * h; r < 2 * h + 2; r++) {
        int G = r * 8 + wid;
        int row = nBase + G * 8 + rin;
        load_lds16(B + (size_t)row * DDIM + t * GBK + cswu,
                   lds + (t & 1) * 32768 + 16384 + G * 512 + lane * 8);
      }
    }
  };

  floatx4 acc[8][4] = {};
  bf16x8 bfr[4][2];

  // prologue: B(0), A(0), B(1) staged in steady-state issue order
  stageBh(0, 0); stageBh(0, 1);
  stageAh(0, 0); stageAh(0, 1);
  stageBh(1, 0); stageBh(1, 1);
  asm volatile("s_waitcnt vmcnt(4)" ::: "memory");   // A(0),B(0) landed
  __builtin_amdgcn_s_barrier();

#pragma unroll 1
  for (int i = 0; i < NT / 2; i++) {
    const int t0 = 2 * i;
    const bool last = (i == NT / 2 - 1);
    // tile t0 (buf 0)
    PHASE(0, 0, true,  stageAh(t0 + 1, 0), );
    PHASE(0, 1, false, stageAh(t0 + 1, 1), );
    PHASE(0, 2, false, stageBh(t0 + 2, 0), );
    PHASE(0, 3, false, stageBh(t0 + 2, 1),
          if (last) { asm volatile("s_waitcnt vmcnt(0)" ::: "memory"); }
          else      { asm volatile("s_waitcnt vmcnt(4)" ::: "memory"); });
    // tile t0+1 (buf 1)
    PHASE(1, 0, true,  stageAh(t0 + 2, 0), );
    PHASE(1, 1, false, stageAh(t0 + 2, 1), );
    PHASE(1, 2, false, stageBh(t0 + 3, 0), );
    PHASE(1, 3, false, stageBh(t0 + 3, 1),
          if (!last) { asm volatile("s_waitcnt vmcnt(4)" ::: "memory"); });
  }

  // epilogue: C write (bf16)
#pragma unroll
  for (int m = 0; m < 8; m++)
#pragma unroll
    for (int n = 0; n < 4; n++) {
      int q = qBase + wm * 128 + m * 16 + lg * 4;
      int col = nBase + wn * 64 + n * 16 + lr;
      ushort* cp = C + (size_t)q * NPAD + col;
#pragma unroll
      for (int r = 0; r < 4; r++) cp[(size_t)r * NPAD] = f2bf(acc[m][n][r]);
    }
}

// ---- per-segment exact top-K multiset: ballot counting + ballot compaction
__global__ __launch_bounds__(256) void topk_seg(const ushort* __restrict__ sims,
                                                ushort* __restrict__ cand) {
  __shared__ ushort smax[256];
  __shared__ ushort list[LCAP2];
  __shared__ int shC, shM, ipart[4];
  const int t = threadIdx.x;
  const int lane = t & 63;
  const int q = blockIdx.x >> 3, seg = blockIdx.x & 7;
  const ushort* base = sims + (size_t)q * NPAD + seg * SEGW2;

  uint v[25];                                  // 50 ordered u16 keys
#pragma unroll
  for (int i = 0; i < 6; i++) {                // 6 x uint4 = 48 keys
    uint4 w = ((const uint4*)base)[i * 256 + t];
    uint ww[4] = {w.x, w.y, w.z, w.w};
#pragma unroll
    for (int e = 0; e < 4; e++) {
      uint u = ww[e];
      uint mm = ((u >> 15) & 0x00010001u) * 0xffffu;
      v[4 * i + e] = (u ^ mm) | (0x80008000u & ~mm);
    }
    if (seg == 7 && (i * 256 + t) >= 1300) {   // pad cols >= 100000
      v[4 * i] = 0; v[4 * i + 1] = 0; v[4 * i + 2] = 0; v[4 * i + 3] = 0;
    }
  }
  {                                            // tail: 2 keys (invalid in seg 7)
    if (seg == 7) {
      v[24] = 0;
    } else {
      uint u = ((const uint*)base)[6144 + t];
      uint mm = ((u >> 15) & 0x00010001u) * 0xffffu;
      v[24] = (u ^ mm) | (0x80008000u & ~mm);
    }
  }
  // thread max
  uint mx = 0;
#pragma unroll
  for (int i = 0; i < 25; i++) {
    uint a = v[i] & 0xffffu, b = v[i] >> 16;
    mx = a > mx ? a : mx;
    mx = b > mx ? b : mx;
  }
  smax[t] = (ushort)mx;
  if (t == 0) shC = 0;
  __syncthreads();

  // L = 100th largest of 256 thread maxima — ballot-popcount counting
  uint m0 = smax[lane], m1 = smax[lane + 64], m2 = smax[lane + 128], m3 = smax[lane + 192];
  uint lo = 0, hi = 65536;
  while (hi - lo > 1) {
    uint mid = (lo + hi) >> 1;
    int c = __popcll(__ballot(m0 >= mid)) + __popcll(__ballot(m1 >= mid)) +
            __popcll(__ballot(m2 >= mid)) + __popcll(__ballot(m3 >= mid));
    if (c >= KTOP) lo = mid; else hi = mid;
  }
  const uint L = lo;

  // ---- ballot compaction of keys >= L into LDS (1 atomic per wave) ----
  const unsigned long long ltm = (1ull << lane) - 1ull;
  int tot = 0;
#pragma unroll
  for (int i = 0; i < 25; i++) {
    tot += __popcll(__ballot((v[i] & 0xffffu) >= L));
    tot += __popcll(__ballot((v[i] >> 16) >= L));
  }
  int wb = 0;
  if (lane == 0) wb = atomicAdd(&shC, tot);
  wb = __shfl(wb, 0);
  int run = wb;
#pragma unroll
  for (int i = 0; i < 25; i++) {
    uint a = v[i] & 0xffffu, b = v[i] >> 16;
    unsigned long long ma = __ballot(a >= L);
    if (a >= L) { int p = run + __popcll(ma & ltm); if (p < LCAP2) list[p] = (ushort)a; }
    run += __popcll(ma);
    unsigned long long mb = __ballot(b >= L);
    if (b >= L) { int p = run + __popcll(mb & ltm); if (p < LCAP2) list[p] = (ushort)b; }
    run += __popcll(mb);
  }
  __syncthreads();
  const int C = shC;

  uint Tkey;
  if (C <= LCAP2) {                            // common path: ballot-count search
    uint lo2 = L, hi2 = 65536;
    while (hi2 - lo2 > 1) {
      uint mid = (lo2 + hi2) >> 1;
      int c = 0;
      for (int j = 0; j < C; j += 64) {
        bool p = (j + lane < C) && ((uint)list[j + lane] >= mid);
        c += __popcll(__ballot(p));
      }
      if (c >= KTOP) lo2 = mid; else hi2 = mid;
    }
    Tkey = lo2;
  } else {                                     // rare fallback: regs + barriers
    uint lo2 = L, hi2 = 65536;
    while (hi2 - lo2 > 1) {
      uint mid = (lo2 + hi2) >> 1;
      int c = 0;
#pragma unroll
      for (int i = 0; i < 25; i++) {
        c += ((v[i] & 0xffffu) >= mid) ? 1 : 0;
        c += ((v[i] >> 16) >= mid) ? 1 : 0;
      }
#pragma unroll
      for (int off = 32; off; off >>= 1) c += __shfl_xor(c, off);
      __syncthreads();
      if (lane == 0) ipart[t >> 6] = c;
      __syncthreads();
      c = ipart[0] + ipart[1] + ipart[2] + ipart[3];
      if (c >= KTOP) lo2 = mid; else hi2 = mid;
    }
    Tkey = lo2;
  }

  // emit segment top-100 multiset (m <= 99 strict keys + tie fill)
  if (t == 0) shM = 0;
  __syncthreads();
  ushort* dst = cand + (size_t)q * 1024 + seg * 128;
  if (C <= LCAP2) {
    for (int i = t; i < C; i += 256) {
      uint u = list[i];
      if (u > Tkey) { int p = atomicAdd(&shM, 1); dst[p] = (ushort)u; }
    }
  } else {
#pragma unroll
    for (int i = 0; i < 25; i++) {
      uint a = v[i] & 0xffffu, b = v[i] >> 16;
      if (a > Tkey) { int p = atomicAdd(&shM, 1); dst[p] = (ushort)a; }
      if (b > Tkey) { int p = atomicAdd(&shM, 1); dst[p] = (ushort)b; }
    }
  }
  __syncthreads();
  for (int i = shM + t; i < KTOP; i += 256) dst[i] = (ushort)Tkey;
}

// ---- merge 8x100 candidates + mean + energy -> out (1 wave / row) --------
__global__ __launch_bounds__(64) void topk_fin(const ushort* __restrict__ cand,
                                               const float* __restrict__ energy,
                                               float* __restrict__ out) {
  const int q = blockIdx.x;
  const int t = threadIdx.x;
  const ushort* row = cand + (size_t)q * 1024;
  ushort kk[16];
#pragma unroll
  for (int s = 0; s < 8; s++) {
    kk[2 * s]     = row[s * 128 + t];                                  // t < 100
    kk[2 * s + 1] = (t + 64 < KTOP) ? row[s * 128 + 64 + t] : (ushort)0;
  }
  uint lo = 0, hi = 65536;
  while (hi - lo > 1) {
    uint mid = (lo + hi) >> 1;
    int c = 0;
#pragma unroll
    for (int i = 0; i < 16; i++) c += ((uint)kk[i] >= mid) ? 1 : 0;
#pragma unroll
    for (int off = 32; off; off >>= 1) c += __shfl_xor(c, off);
    if (c >= KTOP) lo = mid; else hi = mid;
  }
  const uint T = lo;
  float s = 0.f;
  int m = 0;
#pragma unroll
  for (int i = 0; i < 16; i++) {
    if ((uint)kk[i] > T) { s += o16f(kk[i]); m++; }
  }
#pragma unroll
  for (int off = 32; off; off >>= 1) {
    s += __shfl_xor(s, off);
    m += __shfl_xor(m, off);
  }
  if (t == 0) {
    float total = s + (float)(KTOP - m) * o16f((ushort)T);
    out[q] = -(total * (1.0f / KTOP)) * energy[q];
  }
}

extern "C" void kernel_launch(void* const* d_in, const int* in_sizes, int n_in,
                              void* d_out, int out_size, void* d_ws, size_t ws_size,
                              hipStream_t stream) {
  const float* feature     = (const float*)d_in[0];
  const float* logit       = (const float*)d_in[1];
  const float* bank_feas   = (const float*)d_in[2];
  const float* bank_logits = (const float*)d_in[3];
  // d_in[4] is K (device scalar) — problem instance fixes K = 100 (KTOP).
  float* out = (float*)d_out;

  char* ws = (char*)d_ws;
  size_t off = 0;
  auto take = [&](size_t bytes) -> char* {
    char* p = ws + off;
    off = (off + bytes + 255) & ~(size_t)255;
    return p;
  };
  float*  energy = (float*)take((size_t)QROWS * 4);
  float*  conf   = (float*)take((size_t)NPAD * 4);
  ushort* a16    = (ushort*)take((size_t)QROWS * DDIM * 2);
  ushort* b16    = (ushort*)take((size_t)NPAD * DDIM * 2);
  ushort* sims   = (ushort*)take((size_t)QROWS * NPAD * 2);
  ushort* cand   = (ushort*)take((size_t)QROWS * 1024 * 2);
  if (off > ws_size) return;  // needs ~1.02 GB

  lse_rows <<<dim3((NBANK + 3) / 4), dim3(256), 0, stream>>>(bank_logits, conf, NBANK, CDIM);
  bank_sc  <<<dim3(NPAD / 4), dim3(256), 0, stream>>>(bank_feas, conf, b16);
  lse_rows <<<dim3(QROWS / 4), dim3(256), 0, stream>>>(logit, energy, QROWS, CDIM);
  feat_norm<<<dim3(QROWS / 4), dim3(256), 0, stream>>>(feature, a16);
  gemm_sims<<<dim3(GNWG), dim3(512), 0, stream>>>(a16, b16, sims);
  topk_seg <<<dim3(QROWS * 8), dim3(256), 0, stream>>>(sims, cand);
  topk_fin <<<dim3(QROWS), dim3(64), 0, stream>>>(cand, energy, out);
}